// Round 7
// baseline (101.232 us; speedup 1.0000x reference)
//
#include <hip/hip_runtime.h>

typedef __bf16 bf16x8 __attribute__((ext_vector_type(8)));
typedef float f32x4 __attribute__((ext_vector_type(4)));
typedef unsigned short u16;

#define LSEQ 2048
#define DMODEL 1024
#define HEADD 64
#define NBATCH 8

__device__ __forceinline__ u16 cvt(float f) {
  __bf16 h = (__bf16)f;               // native v_cvt (RNE)
  return __builtin_bit_cast(u16, h);
}

// ---------------------------------------------------------------------------
// Kernel 0: pack W [1024][64] fp32 into MFMA B-FRAGMENT order (bf16):
//   wp[((p*4 + c)*32 + ks)*512 + lane*8 + j] = W_p[k = ks*32 + 8*(lane>>4) + j]
//                                                  [col = 16*c + (lane&15)]
// -> a wave's B-frag load in proj is ONE contiguous 1KB read.
// ---------------------------------------------------------------------------
__global__ __launch_bounds__(256) void wt_kernel(
    const float* __restrict__ Wk, const float* __restrict__ Wq,
    const float* __restrict__ Wv, u16* __restrict__ wp) {
  int idx = blockIdx.x * 256 + threadIdx.x;   // 0 .. 3*4*32*512-1 (196608)
  int j = idx & 7;
  int lane = (idx >> 3) & 63;
  int ks = (idx >> 9) & 31;
  int c = (idx >> 14) & 3;
  int p = idx >> 16;
  const float* W = (p == 0) ? Wk : ((p == 1) ? Wq : Wv);
  int k = ks * 32 + 8 * (lane >> 4) + j;
  int col = 16 * c + (lane & 15);
  wp[idx] = cvt(W[(size_t)k * HEADD + col]);
}

// ---------------------------------------------------------------------------
// Kernel 1: projections = staged-contiguous A (R3) + fragment-packed W (R6).
// Block 256 thr (4 waves) owns 64 rows; K chunked by 128 cols, double-buffered
// XOR-swizzled [64][128] bf16 LDS tile. Staging instr = 2 rows x 512B
// contiguous; W-frag instr = 1KB contiguous (L2-hot). vmcnt-FIFO order per
// chunk: W (oldest) -> sched_barrier -> A-stage next chunk (youngest, in
// flight across compute) -> ds_read_b128+MFMA -> vmcnt(0)+commit+barrier.
// p==0 -> K bf16 ; p==1 -> Q*0.125 ; p==2 -> V^T [b][64][2048]
// ---------------------------------------------------------------------------
__global__ __launch_bounds__(256) void proj_kernel(
    const float* __restrict__ ik, const float* __restrict__ iq, const float* __restrict__ iv,
    const u16* __restrict__ wp, u16* __restrict__ Kb, u16* __restrict__ Qb,
    u16* __restrict__ Vt) {
  __shared__ __align__(16) u16 Asw[2][64 * 128];  // 2 x 16 KB swizzled bf16
  int p = blockIdx.y;
  const float* A = (p == 0) ? ik : ((p == 1) ? iq : iv);
  const u16* Wp = wp + (size_t)p * 4 * 32 * 512;   // [c][ks][512]
  int t = threadIdx.x;
  int lane = t & 63;
  int wv = t >> 6;
  int l15 = lane & 15, g = lane >> 4;
  int rowbase = blockIdx.x * 64;
  const float* srcbase = A + (size_t)rowbase * DMODEL;

  // staging map: piece i (0..7): row = i*8 + (t>>5), float-col = (t&31)*4
  int srow0 = t >> 5;
  int scol = (t & 31) * 4;

  float4 stg[8];
  auto issue = [&](int kc) {
#pragma unroll
    for (int i = 0; i < 8; ++i) {
      int row = i * 8 + srow0;
      stg[i] = *(const float4*)(srcbase + (size_t)row * DMODEL + kc + scol);
    }
  };
  auto commit = [&](int buf) {
    char* base = (char*)&Asw[buf][0];
#pragma unroll
    for (int i = 0; i < 8; ++i) {
      int row = i * 8 + srow0;
      ushort4 pk;
      pk.x = cvt(stg[i].x); pk.y = cvt(stg[i].y);
      pk.z = cvt(stg[i].z); pk.w = cvt(stg[i].w);
      int byte = row * 256 + ((scol * 2) ^ ((row & 7) << 4));
      *(ushort4*)(base + byte) = pk;
    }
  };

  f32x4 acc[4] = {};  // [c]: row = rowbase+16wv+4g+r, col = 16c+l15
  int arow = 16 * wv + l15;
  int abase = arow * 256;
  int aswz = (l15 & 7) << 4;

  issue(0);
  commit(0);
  __syncthreads();

  for (int c8 = 0; c8 < 8; ++c8) {
    // (1) W fragments for the CURRENT chunk -> registers (oldest in vmcnt
    // queue; contiguous 1KB each, L2-hot, return fast)
    bf16x8 wfr[4][4];
#pragma unroll
    for (int ks = 0; ks < 4; ++ks)
#pragma unroll
      for (int c = 0; c < 4; ++c)
        wfr[ks][c] = *(const bf16x8*)(Wp + ((size_t)c * 32 + c8 * 4 + ks) * 512 + lane * 8);

    __builtin_amdgcn_sched_barrier(0);

    // (2) A-stage for the NEXT chunk (HBM, youngest -> stays in flight)
    if (c8 < 7) issue((c8 + 1) * 128);

    __builtin_amdgcn_sched_barrier(0);

    // (3) compute current chunk from LDS
    const char* lbase = (const char*)&Asw[c8 & 1][0];
#pragma unroll
    for (int ks = 0; ks < 4; ++ks) {
      bf16x8 af = *(const bf16x8*)(lbase + abase + ((ks * 64 + 16 * g) ^ aswz));
#pragma unroll
      for (int c = 0; c < 4; ++c)
        acc[c] = __builtin_amdgcn_mfma_f32_16x16x32_bf16(af, wfr[ks][c], acc[c], 0, 0, 0);
    }

    // (4) land the prefetch, write LDS, swap
    if (c8 < 7) commit((c8 + 1) & 1);
    __syncthreads();
  }

  int rb2 = rowbase + 16 * wv;
  if (p == 2) {
    // store V transposed: Vt[b][d][tok], pack 4 consecutive tokens -> 8B store
    int row0 = rb2 + 4 * g;
    int b = row0 >> 11, tok = row0 & 2047;
#pragma unroll
    for (int c = 0; c < 4; ++c) {
      int d = 16 * c + l15;
      ushort4 pk;
      pk.x = cvt(acc[c][0]); pk.y = cvt(acc[c][1]);
      pk.z = cvt(acc[c][2]); pk.w = cvt(acc[c][3]);
      *(ushort4*)(Vt + ((size_t)b * HEADD + d) * LSEQ + tok) = pk;
    }
  } else {
    u16* dst = (p == 0) ? Kb : Qb;
    float s = (p == 1) ? 0.125f : 1.0f;  // fold softmax scale into Q (exact pow2)
#pragma unroll
    for (int c = 0; c < 4; ++c)
#pragma unroll
      for (int r = 0; r < 4; ++r)
        dst[(size_t)(rb2 + 4 * g + r) * HEADD + 16 * c + l15] = cvt(acc[c][r] * s);
  }
}

// ---------------------------------------------------------------------------
// Kernel 2: causal flash attention. 2 waves/block, wave owns 16 q-rows.
// Swapped QK^T: S^T = mfma(K, Q^T) so lane's scores all belong to q = lane&15.
// P transposed to PV A-frag layout via small padded per-wave LDS buffer.
// V^T gives contiguous 16B PV B-frag loads.
// ---------------------------------------------------------------------------
__global__ __launch_bounds__(128) void attn_kernel(
    const u16* __restrict__ Kb, const u16* __restrict__ Qb, const u16* __restrict__ Vt,
    float* __restrict__ out) {
  __shared__ __align__(16) u16 plds[2][16 * 40];  // per-wave P tile [16q][32k], pad->40
  int lane = threadIdx.x & 63;
  int wv = threadIdx.x >> 6;
  int l15 = lane & 15, g = lane >> 4;
  int b = blockIdx.y;
  int qt = 63 - (int)blockIdx.x;          // heavy tiles first
  int qbase = qt * 32 + wv * 16;          // within batch

  const u16* Qp = Qb + ((size_t)b * LSEQ + qbase) * HEADD;
  const u16* Kp = Kb + (size_t)b * LSEQ * HEADD;
  const u16* Vp = Vt + (size_t)b * HEADD * LSEQ;

  bf16x8 qf[2];
#pragma unroll
  for (int ds = 0; ds < 2; ++ds)
    qf[ds] = *(const bf16x8*)(Qp + (size_t)l15 * HEADD + 32 * ds + 8 * g);

  f32x4 acc[4] = {};        // [c]: reg r -> q-row qbase+4g+r, col d=16c+l15
  float m = -1e30f, lsum = 0.f;
  int q_abs = qbase + l15;
  int ntiles = (qbase + 47) >> 5;

  for (int t = 0; t < ntiles; ++t) {
    int kbase = t * 32;
    f32x4 sacc[2] = {};     // [f]: key = kbase+16f+4g+r, q = qbase+l15
#pragma unroll
    for (int f = 0; f < 2; ++f)
#pragma unroll
      for (int ds = 0; ds < 2; ++ds) {
        bf16x8 kf = *(const bf16x8*)(Kp + (size_t)(kbase + 16 * f + l15) * HEADD + 32 * ds + 8 * g);
        sacc[f] = __builtin_amdgcn_mfma_f32_16x16x32_bf16(kf, qf[ds], sacc[f], 0, 0, 0);
      }

    // causal mask + row-max (row == this lane's q)
    float sv[2][4];
    float tmax = -1e30f;
#pragma unroll
    for (int f = 0; f < 2; ++f)
#pragma unroll
      for (int r = 0; r < 4; ++r) {
        int key = kbase + 16 * f + 4 * g + r;
        float s = (key <= q_abs) ? sacc[f][r] : -1e30f;
        sv[f][r] = s;
        tmax = fmaxf(tmax, s);
      }
    tmax = fmaxf(tmax, __shfl_xor(tmax, 16));
    tmax = fmaxf(tmax, __shfl_xor(tmax, 32));
    float mnew = fmaxf(m, tmax);
    float al = __expf(m - mnew);
    float pv[2][4];
    float rs = 0.f;
#pragma unroll
    for (int f = 0; f < 2; ++f)
#pragma unroll
      for (int r = 0; r < 4; ++r) {
        pv[f][r] = __expf(sv[f][r] - mnew);
        rs += pv[f][r];
      }
    rs += __shfl_xor(rs, 16);
    rs += __shfl_xor(rs, 32);
    lsum = lsum * al + rs;
    m = mnew;

    // rescale O accumulator: row 4g+r's factor lives at lane (4g+r) (group 0 copy)
    float alr[4];
#pragma unroll
    for (int r = 0; r < 4; ++r) alr[r] = __shfl(al, 4 * g + r);
#pragma unroll
    for (int c = 0; c < 4; ++c)
#pragma unroll
      for (int r = 0; r < 4; ++r) acc[c][r] *= alr[r];

    // P -> LDS in PV A-frag layout: P[q=l15][key 16f+4g + r]
#pragma unroll
    for (int f = 0; f < 2; ++f) {
      ushort4 pk;
      pk.x = cvt(pv[f][0]); pk.y = cvt(pv[f][1]);
      pk.z = cvt(pv[f][2]); pk.w = cvt(pv[f][3]);
      *(ushort4*)&plds[wv][l15 * 40 + 16 * f + 4 * g] = pk;
    }
    bf16x8 ap = *(const bf16x8*)&plds[wv][l15 * 40 + 8 * g];

    // PV: B-frag = V[kbase+8g+j][16c+l15] = Vt[16c+l15][kbase+8g+j] (contiguous)
#pragma unroll
    for (int c = 0; c < 4; ++c) {
      bf16x8 vf = *(const bf16x8*)(Vp + (size_t)(16 * c + l15) * LSEQ + kbase + 8 * g);
      acc[c] = __builtin_amdgcn_mfma_f32_16x16x32_bf16(ap, vf, acc[c], 0, 0, 0);
    }
  }

  // normalize and store fp32 output
  float li[4];
#pragma unroll
  for (int r = 0; r < 4; ++r) {
    float lv = __shfl(lsum, 4 * g + r);
    li[r] = 1.0f / lv;
  }
#pragma unroll
  for (int c = 0; c < 4; ++c)
#pragma unroll
    for (int r = 0; r < 4; ++r)
      out[((size_t)b * LSEQ + qbase + 4 * g + r) * HEADD + 16 * c + l15] = acc[c][r] * li[r];
}

// ---------------------------------------------------------------------------
extern "C" void kernel_launch(void* const* d_in, const int* in_sizes, int n_in,
                              void* d_out, int out_size, void* d_ws, size_t ws_size,
                              hipStream_t stream) {
  const float* idx_k = (const float*)d_in[0];
  const float* idx_q = (const float*)d_in[1];
  const float* idx_v = (const float*)d_in[2];
  // d_in[3] = msk : causal mask is applied analytically, never read
  const float* Wk = (const float*)d_in[4];
  const float* Wq = (const float*)d_in[5];
  const float* Wv = (const float*)d_in[6];
  float* out = (float*)d_out;

  char* ws = (char*)d_ws;
  const size_t WT_BYTES = (size_t)3 * 4 * 32 * 512 * 2;          // 384 KB packed W
  const size_t MAT_BYTES = (size_t)NBATCH * LSEQ * HEADD * 2;    // 2 MB each
  u16* wp = (u16*)ws;
  u16* Kb = (u16*)(ws + WT_BYTES);
  u16* Qb = (u16*)(ws + WT_BYTES + MAT_BYTES);
  u16* Vt = (u16*)(ws + WT_BYTES + 2 * MAT_BYTES);

  hipLaunchKernelGGL(wt_kernel, dim3(768), dim3(256), 0, stream, Wk, Wq, Wv, wp);
  hipLaunchKernelGGL(proj_kernel, dim3(256, 3), dim3(256), 0, stream,
                     idx_k, idx_q, idx_v, wp, Kb, Qb, Vt);
  hipLaunchKernelGGL(attn_kernel, dim3(64, NBATCH), dim3(128), 0, stream, Kb, Qb, Vt, out);
}